// Round 1
// baseline (92.630 us; speedup 1.0000x reference)
//
#include <hip/hip_runtime.h>
#include <math.h>

#define N_FFT 16384
#define MVAL 64
#define ROWS 1024   // B*Cin = B*Cout = 16*64

// ---------------- ws layout (float offsets) ----------------
// castab : [16384]                       @ 0
// casA   : [16384][64]  cas(2*pi*n*m/N) @ 16384
// casB   : [64][16384]                  @ 1064960
// partial: [64][1024][64]               @ 2113536
// xh     : [1024][64]                   @ 6307840
// lowT   : [64][1024]                   @ 6373376
#define OFF_TAB  0
#define OFF_CASA 16384
#define OFF_CASB 1064960
#define OFF_PART 2113536
#define OFF_XH   6307840
#define OFF_LOWT 6373376

__global__ __launch_bounds__(256) void k_tab(float* __restrict__ castab) {
    int i = blockIdx.x * 256 + threadIdx.x;
    if (i < N_FFT) {
        double ang = 6.283185307179586476925287 * (double)i / (double)N_FFT;
        castab[i] = (float)(cos(ang) + sin(ang));
    }
}

__global__ __launch_bounds__(256) void k_fill(const float* __restrict__ castab,
                                              float* __restrict__ casA,
                                              float* __restrict__ casB) {
    int tid = blockIdx.x * 256 + threadIdx.x;   // 0 .. 2*2^20-1
    if (tid < (1 << 20)) {
        int n = tid >> 6, m = tid & 63;
        casA[tid] = castab[(n * m) & (N_FFT - 1)];
    } else {
        int t2 = tid - (1 << 20);
        int m = t2 >> 14, n = t2 & (N_FFT - 1);
        casB[t2] = castab[(m * n) & (N_FFT - 1)];
    }
}

// Step A: partial[ks][r][m] = sum_{k in split ks} x[r][k] * casA[k][m]
// grid 512 = 8 rowblocks * 64 ksplits; block 256
__global__ __launch_bounds__(256) void kA(const float* __restrict__ x,
                                          const float* __restrict__ casA,
                                          float* __restrict__ partial) {
    const int rb = blockIdx.x & 7;
    const int ks = blockIdx.x >> 3;
    const int rowbase = rb * 128;
    const int k0base = ks * 256;

    __shared__ float xs[128 * 65];   // [r][k] padded stride 65
    __shared__ float cs[64 * 64];    // [k][m]

    const int t  = threadIdx.x;
    const int rg = t & 31;           // row group, rows rg + 32*j
    const int mg = t >> 5;           // 0..7 -> m = mg*8 .. +7

    float acc[4][8];
#pragma unroll
    for (int j = 0; j < 4; ++j)
#pragma unroll
        for (int q = 0; q < 8; ++q) acc[j][q] = 0.0f;

    for (int kc = 0; kc < 256; kc += 64) {
        const int k0 = k0base + kc;
        __syncthreads();
        // stage x[rowbase..+127][k0..k0+63]
#pragma unroll
        for (int rep = 0; rep < 8; ++rep) {
            int flat = rep * 256 + t;      // 0..2047
            int r  = flat >> 4;            // 0..127
            int kq = flat & 15;            // 0..15
            const float4 v = *reinterpret_cast<const float4*>(
                &x[(size_t)(rowbase + r) * N_FFT + k0 + kq * 4]);
            float* dst = &xs[r * 65 + kq * 4];
            dst[0] = v.x; dst[1] = v.y; dst[2] = v.z; dst[3] = v.w;
        }
        // stage casA[k0..+63][0..63]
#pragma unroll
        for (int rep = 0; rep < 4; ++rep) {
            int flat = rep * 256 + t;      // 0..1023
            int kk = flat >> 4;
            int mq = flat & 15;
            *reinterpret_cast<float4*>(&cs[kk * 64 + mq * 4]) =
                *reinterpret_cast<const float4*>(&casA[(size_t)(k0 + kk) * 64 + mq * 4]);
        }
        __syncthreads();

        for (int kk = 0; kk < 64; ++kk) {
            float xv[4];
#pragma unroll
            for (int j = 0; j < 4; ++j) xv[j] = xs[(rg + 32 * j) * 65 + kk];
            const float4 c0 = *reinterpret_cast<const float4*>(&cs[kk * 64 + mg * 8]);
            const float4 c1 = *reinterpret_cast<const float4*>(&cs[kk * 64 + mg * 8 + 4]);
            const float cv[8] = {c0.x, c0.y, c0.z, c0.w, c1.x, c1.y, c1.z, c1.w};
#pragma unroll
            for (int j = 0; j < 4; ++j)
#pragma unroll
                for (int q = 0; q < 8; ++q)
                    acc[j][q] = fmaf(xv[j], cv[q], acc[j][q]);
        }
    }

    // write partial[ks][rowbase + rg + 32j][mg*8 .. +7]
#pragma unroll
    for (int j = 0; j < 4; ++j) {
        size_t r = (size_t)rowbase + rg + 32 * j;
        float* p = &partial[(((size_t)ks << 10) + r) * 64 + mg * 8];
        *reinterpret_cast<float4*>(p)     = make_float4(acc[j][0], acc[j][1], acc[j][2], acc[j][3]);
        *reinterpret_cast<float4*>(p + 4) = make_float4(acc[j][4], acc[j][5], acc[j][6], acc[j][7]);
    }
}

// reduce 64 partials -> xh[r][m]; grid 64 * 256 threads, float4 granularity
__global__ __launch_bounds__(256) void kR(const float* __restrict__ partial,
                                          float* __restrict__ xh) {
    int idx4 = blockIdx.x * 256 + threadIdx.x;   // 0..16383
    float4 s = make_float4(0.f, 0.f, 0.f, 0.f);
    for (int sp = 0; sp < 64; ++sp) {
        const float4 v = *reinterpret_cast<const float4*>(&partial[((size_t)sp << 16) + idx4 * 4]);
        s.x += v.x; s.y += v.y; s.z += v.z; s.w += v.w;
    }
    *reinterpret_cast<float4*>(&xh[idx4 * 4]) = s;
}

// Step B: lowT[m][b*64+o] = sum_i xh[b*64+i][m] * w[(o*64+i)*64+m]
// grid (64, 16) = (o, b); 64 threads = m
__global__ __launch_bounds__(64) void kB(const float* __restrict__ xh,
                                         const float* __restrict__ w,
                                         float* __restrict__ lowT) {
    const int o = blockIdx.x, b = blockIdx.y, m = threadIdx.x;
    float acc = 0.0f;
    for (int i = 0; i < 64; ++i) {
        acc = fmaf(xh[(size_t)((b * 64 + i) * 64) + m],
                   w[(size_t)((o * 64 + i) * 64) + m], acc);
    }
    lowT[(size_t)m * ROWS + b * 64 + o] = acc;
}

// Step C: out[r][n] = (1/N) * sum_m lowT[m][r] * casB[m][n]
// grid 1024 = 8 rowblocks * 128 nblocks; block 256
__global__ __launch_bounds__(256) void kC(const float* __restrict__ lowT,
                                          const float* __restrict__ casB,
                                          float* __restrict__ out) {
    const int nb = blockIdx.x & 127;
    const int rb = blockIdx.x >> 7;
    const int rowbase = rb * 128;
    const int n0 = nb * 128;

    __shared__ float ls[64 * 128];    // [m][r]
    __shared__ float csb[64 * 128];   // [m][n]

    const int t  = threadIdx.x;
    const int ng = t & 7;             // n chunks: n = q*32 + ng*4 + j
    const int rg = t >> 3;            // 0..31 -> rows rg*4 .. +3

#pragma unroll
    for (int rep = 0; rep < 8; ++rep) {
        int flat = rep * 256 + t;     // 0..2047
        int m  = flat >> 5;           // 0..63
        int rq = flat & 31;
        *reinterpret_cast<float4*>(&ls[m * 128 + rq * 4]) =
            *reinterpret_cast<const float4*>(&lowT[(size_t)m * ROWS + rowbase + rq * 4]);
        *reinterpret_cast<float4*>(&csb[m * 128 + rq * 4]) =
            *reinterpret_cast<const float4*>(&casB[(size_t)m * N_FFT + n0 + rq * 4]);
    }
    __syncthreads();

    float acc[4][16];
#pragma unroll
    for (int j = 0; j < 4; ++j)
#pragma unroll
        for (int q = 0; q < 16; ++q) acc[j][q] = 0.0f;

    for (int k = 0; k < 64; ++k) {
        const float4 lv = *reinterpret_cast<const float4*>(&ls[k * 128 + rg * 4]);
        const float l[4] = {lv.x, lv.y, lv.z, lv.w};
        float cv[16];
#pragma unroll
        for (int q = 0; q < 4; ++q) {
            const float4 c = *reinterpret_cast<const float4*>(&csb[k * 128 + q * 32 + ng * 4]);
            cv[q * 4 + 0] = c.x; cv[q * 4 + 1] = c.y; cv[q * 4 + 2] = c.z; cv[q * 4 + 3] = c.w;
        }
#pragma unroll
        for (int j = 0; j < 4; ++j)
#pragma unroll
            for (int q = 0; q < 16; ++q)
                acc[j][q] = fmaf(l[j], cv[q], acc[j][q]);
    }

    const float sc = 1.0f / (float)N_FFT;
#pragma unroll
    for (int j = 0; j < 4; ++j) {
        size_t row = (size_t)rowbase + rg * 4 + j;
#pragma unroll
        for (int q = 0; q < 4; ++q) {
            float4 v = make_float4(acc[j][q * 4 + 0] * sc, acc[j][q * 4 + 1] * sc,
                                   acc[j][q * 4 + 2] * sc, acc[j][q * 4 + 3] * sc);
            *reinterpret_cast<float4*>(&out[row * N_FFT + n0 + q * 32 + ng * 4]) = v;
        }
    }
}

extern "C" void kernel_launch(void* const* d_in, const int* in_sizes, int n_in,
                              void* d_out, int out_size, void* d_ws, size_t ws_size,
                              hipStream_t stream) {
    const float* x = (const float*)d_in[0];
    const float* w = (const float*)d_in[1];
    float* out = (float*)d_out;
    float* ws  = (float*)d_ws;

    float* castab  = ws + OFF_TAB;
    float* casA    = ws + OFF_CASA;
    float* casB    = ws + OFF_CASB;
    float* partial = ws + OFF_PART;
    float* xh      = ws + OFF_XH;
    float* lowT    = ws + OFF_LOWT;

    k_tab<<<64, 256, 0, stream>>>(castab);
    k_fill<<<8192, 256, 0, stream>>>(castab, casA, casB);
    kA<<<512, 256, 0, stream>>>(x, casA, partial);
    kR<<<64, 256, 0, stream>>>(partial, xh);
    kB<<<dim3(64, 16), 64, 0, stream>>>(xh, w, lowT);
    kC<<<1024, 256, 0, stream>>>(lowT, casB, out);
}